// Round 2
// baseline (4302.576 us; speedup 1.0000x reference)
//
#include <hip/hip_runtime.h>
#include <hip/hip_bf16.h>
#include <cstdint>
#include <cstddef>

// LSTM encoder: T=256, B=64, VOCAB=32000, E=512, H=1024
#define T_STEPS 256
#define BATCH   64
#define DE      512
#define DH      1024
#define G4      4096   // 4*DH
#define NBLK    128    // recurrence blocks; each owns 8 hidden units

typedef short  bf16x8 __attribute__((ext_vector_type(8)));   // 8 bf16 = 4 VGPRs
typedef float  f32x4  __attribute__((ext_vector_type(4)));
typedef unsigned long long u64;

__device__ __forceinline__ unsigned short bf_bits(__hip_bfloat16 h) {
    union { __hip_bfloat16 h; unsigned short u; } x; x.h = h; return x.u;
}
__device__ __forceinline__ float b2f(unsigned short u) {
    union { float f; unsigned v; } x; x.v = ((unsigned)u) << 16; return x.f;
}

__device__ __forceinline__ void async_copy16(const void* gsrc, void* ldst) {
    __builtin_amdgcn_global_load_lds(
        (const __attribute__((address_space(1))) unsigned int*)gsrc,
        (__attribute__((address_space(3))) unsigned int*)ldst,
        16, 0, 0);
}

// relaxed agent-scope (LLC-coherent) accessors
__device__ __forceinline__ u64 llc_load64(const u64* p) {
    return __hip_atomic_load(p, __ATOMIC_RELAXED, __HIP_MEMORY_SCOPE_AGENT);
}
__device__ __forceinline__ void llc_store64(u64* p, u64 v) {
    __hip_atomic_store(p, v, __ATOMIC_RELAXED, __HIP_MEMORY_SCOPE_AGENT);
}
__device__ __forceinline__ unsigned llc_load32(const unsigned* p) {
    return __hip_atomic_load(p, __ATOMIC_RELAXED, __HIP_MEMORY_SCOPE_AGENT);
}
__device__ __forceinline__ void llc_store32(unsigned* p, unsigned v) {
    __hip_atomic_store(p, v, __ATOMIC_RELAXED, __HIP_MEMORY_SCOPE_AGENT);
}

// ---------------- fp32 -> bf16 convert (8 elems/thread) ----------------
__global__ void k_f32_to_bf16(const float* __restrict__ src,
                              __hip_bfloat16* __restrict__ dst, int n8) {
    int i = blockIdx.x * blockDim.x + threadIdx.x;
    if (i >= n8) return;
    const float4* s = (const float4*)src + (size_t)i * 2;
    float4 a = s[0], b = s[1];
    union { unsigned short u[8]; uint4 v; } o;
    o.u[0] = bf_bits(__float2bfloat16(a.x));
    o.u[1] = bf_bits(__float2bfloat16(a.y));
    o.u[2] = bf_bits(__float2bfloat16(a.z));
    o.u[3] = bf_bits(__float2bfloat16(a.w));
    o.u[4] = bf_bits(__float2bfloat16(b.x));
    o.u[5] = bf_bits(__float2bfloat16(b.y));
    o.u[6] = bf_bits(__float2bfloat16(b.z));
    o.u[7] = bf_bits(__float2bfloat16(b.w));
    *((uint4*)dst + i) = o.v;
}

// ---------------- embedding gather + bf16 convert ----------------
__global__ void k_gather(const int* __restrict__ xs, const float* __restrict__ emb,
                         __hip_bfloat16* __restrict__ e_bf) {
    int tid = blockIdx.x * 256 + threadIdx.x;
    int r = tid >> 6, ch = tid & 63;
    int v = xs[r];
    const float4* s = (const float4*)(emb + (size_t)v * DE + ch * 8);
    float4 a = s[0], b = s[1];
    union { unsigned short u[8]; uint4 v4; } o;
    o.u[0] = bf_bits(__float2bfloat16(a.x));
    o.u[1] = bf_bits(__float2bfloat16(a.y));
    o.u[2] = bf_bits(__float2bfloat16(a.z));
    o.u[3] = bf_bits(__float2bfloat16(a.w));
    o.u[4] = bf_bits(__float2bfloat16(b.x));
    o.u[5] = bf_bits(__float2bfloat16(b.y));
    o.u[6] = bf_bits(__float2bfloat16(b.z));
    o.u[7] = bf_bits(__float2bfloat16(b.w));
    *((uint4*)(e_bf + (size_t)r * DE) + ch) = o.v4;
}

// ---------------- x_gates GEMM -> permuted bf16 layout ----------------
// xgp[t][blk][gate][unit][batch] : (((t*128+blk)*4+g)*8+u)*64 + b
__global__ void k_gemm_xg(const __hip_bfloat16* __restrict__ A,   // [16384][512]
                          const __hip_bfloat16* __restrict__ Bt,  // [4096][512]
                          const float* __restrict__ bih, const float* __restrict__ bhh,
                          __hip_bfloat16* __restrict__ xgp) {
    __shared__ __align__(16) __hip_bfloat16 sA[128 * 32];
    __shared__ __align__(16) __hip_bfloat16 sB[128 * 32];
    const int bm = blockIdx.x >> 5;    // 128 M-tiles
    const int bn = blockIdx.x & 31;    // 32 N-tiles
    const int tid = threadIdx.x;
    const int l = tid & 63, w = tid >> 6;
    const int wm = w >> 1, wn = w & 1;
    const int lrow = l & 15, lq = l >> 4;

    f32x4 acc[4][4] = {};

    for (int kb = 0; kb < 512; kb += 32) {
#pragma unroll
        for (int q = 0; q < 2; ++q) {
            int c = q * 256 + tid;
            int row = c >> 2, seg = c & 3;
            async_copy16(A + (size_t)(bm * 128 + row) * 512 + kb + seg * 8, &sA[c * 8]);
            async_copy16(Bt + (size_t)(bn * 128 + row) * 512 + kb + seg * 8, &sB[c * 8]);
        }
        __syncthreads();
        bf16x8 af[4], bq[4];
#pragma unroll
        for (int mt = 0; mt < 4; ++mt)
            af[mt] = *(const bf16x8*)&sA[(wm * 64 + mt * 16 + lrow) * 32 + lq * 8];
#pragma unroll
        for (int nt = 0; nt < 4; ++nt)
            bq[nt] = *(const bf16x8*)&sB[(wn * 64 + nt * 16 + lrow) * 32 + lq * 8];
#pragma unroll
        for (int mt = 0; mt < 4; ++mt)
#pragma unroll
            for (int nt = 0; nt < 4; ++nt)
                acc[mt][nt] = __builtin_amdgcn_mfma_f32_16x16x32_bf16(
                    af[mt], bq[nt], acc[mt][nt], 0, 0, 0);
        __syncthreads();
    }

#pragma unroll
    for (int nt = 0; nt < 4; ++nt) {
        int n = bn * 128 + wn * 64 + nt * 16 + lrow;
        int g = n >> 10, j = n & 1023, blk = j >> 3, u = j & 7;
        float bias = bih[n] + bhh[n];
#pragma unroll
        for (int mt = 0; mt < 4; ++mt) {
#pragma unroll
            for (int r = 0; r < 4; ++r) {
                int m = bm * 128 + wm * 64 + mt * 16 + lq * 4 + r;
                int t = m >> 6, b = m & 63;
                xgp[(((size_t)(t * NBLK + blk) * 4 + g) * 8 + u) * 64 + b] =
                    __float2bfloat16(acc[mt][nt][r] + bias);
            }
        }
    }
}

// ---------------- persistent LSTM recurrence ----------------
// 128 blocks x 256 thr; block owns units j0=8*bk (32 gate rows).
// Whh slice LDS-resident (64 KB); c register-resident; h exchanged through the
// LLC via relaxed agent-scope 8B atomics, triple-buffered.
//
// hbuf layout (LANE-MAJOR): u64 index = (aib/2)*64 + chunk*2 + half,
// where aib = lq*128 + w*32 + lrow*2 is a lane's chunk-local u64 pair index.
// A lane's 32 chunk-fragments are 512 contiguous bytes -> the full-K prefetch
// (64 x 8B llc loads) shares ONE base register with immediate offsets 0..504.
//
// Per-step protocol (vs 2236us baseline):
//  - full-K prefetch: all 64 h loads issued before the MFMA loop (1 LLC
//    latency instead of 4 serialized ones; 8-deep pipeline was L/8-limited)
//  - out[] HBM stores deferred until AFTER the flag store (their store-ack no
//    longer sits inside the pre-flag vmcnt(0)); they drain during the poll
//  - every wave polls all 128 flags itself (lane l checks pair 2l,2l+1 via one
//    8B LLC load) -> no post-poll __syncthreads, each wave starts its next
//    prefetch the moment readiness is visible
__global__ void __launch_bounds__(256, 1) k_lstm(
        const __hip_bfloat16* __restrict__ xgp,   // [256][128][4][8][64]
        const __hip_bfloat16* __restrict__ Whh,   // [4096][1024] row-major
        __hip_bfloat16* __restrict__ hbuf,        // 3 x 65536 elems, lane-major layout
        float* __restrict__ out,
        unsigned* __restrict__ flags) {           // [128], zeroed per call
    __shared__ __hip_bfloat16 sW[32768];          // 64 KB: [nt2][kb32][q4][col16][8]
    __shared__ __align__(8) __hip_bfloat16 sPack[512];
    const int tid = threadIdx.x, l = tid & 63, w = tid >> 6;
    const int lrow = l & 15, lq = l >> 4;
    const int bk = blockIdx.x;

    // load Whh slice -> LDS, frag-contiguous
#pragma unroll
    for (int f = 0; f < 16; ++f) {
        int fi = f * 256 + tid;                  // frag index 0..4095
        int col = fi & 15, q = (fi >> 4) & 3, kb = (fi >> 6) & 31, nt = fi >> 11;
        int g = (nt * 16 + col) >> 3, u = col & 7;
        async_copy16(Whh + (size_t)(g * DH + bk * 8 + u) * DH + kb * 32 + q * 8,
                     &sW[fi * 8]);
    }
    // zero my slice of h buffer 0 through the LLC (any bijection over the
    // 16384 u64s works for zeroing; layout-independent)
    if (tid < 128)
        llc_store64((u64*)hbuf + bk * 128 + tid, 0ull);
    asm volatile("s_waitcnt vmcnt(0)" ::: "memory");
    __syncthreads();
    if (tid == 0) llc_store32(&flags[bk], 1u);
    if (tid < 128)
        while (llc_load32(&flags[tid]) < 1u) __builtin_amdgcn_s_sleep(2);
    __syncthreads();

    const int u = l & 7, halfsel = (l >> 3) & 1;
    const int b0 = w * 16 + lq * 4;
    const int aib = lq * 128 + w * 32 + lrow * 2;   // chunk-local u64 pair base
    const int jout = bk * 8 + u;                    // hidden-unit column in out
    const u64* f64 = (const u64*)flags;
    // producer store index (lane-major layout): pst_c = chunk-local u64 idx
    const int pst_c = ((bk & 3) << 7) + tid;        // valid for tid<128
    const int pst_idx = ((pst_c >> 1) << 6) + ((bk >> 2) << 1) + (pst_c & 1);
    float creg[4] = {0.f, 0.f, 0.f, 0.f};

    for (int t = 0; t < T_STEPS; ++t) {
        const u64* hin  = (const u64*)hbuf + (size_t)(t % 3) * 16384;
        u64*       hout = (u64*)hbuf + (size_t)((t + 1) % 3) * 16384;

        // this step's xg (read-only, plain cached loads)
        const __hip_bfloat16* xgt = xgp + (size_t)t * (NBLK * 2048) + (size_t)bk * 2048;
        ushort4 x0 = *(const ushort4*)(xgt + (halfsel * 8 + u) * 64 + b0);
        ushort4 x1 = *(const ushort4*)(xgt + ((2 + halfsel) * 8 + u) * 64 + b0);

        // full-K prefetch: all 32 chunks (64 x 8B) in flight at once.
        // lane-major layout -> one base reg, imm offsets 0..504 bytes.
        const u64* hl = hin + ((aib >> 1) << 6);
        u64 alo[32], ahi[32];
#pragma unroll
        for (int p = 0; p < 32; ++p) {
            alo[p] = llc_load64(hl + 2 * p);
            ahi[p] = llc_load64(hl + 2 * p + 1);
        }

        f32x4 a00 = {}, a01 = {}, a10 = {}, a11 = {};
#pragma unroll
        for (int kb = 0; kb < 32; ++kb) {
            union { u64 q[2]; bf16x8 v; } A;
            A.q[0] = alo[kb]; A.q[1] = ahi[kb];
            bf16x8 b0f = *(const bf16x8*)&sW[(kb * 4 + lq) * 128 + lrow * 8];
            bf16x8 b1f = *(const bf16x8*)&sW[16384 + (kb * 4 + lq) * 128 + lrow * 8];
            if (kb & 1) {
                a01 = __builtin_amdgcn_mfma_f32_16x16x32_bf16(A.v, b0f, a01, 0, 0, 0);
                a11 = __builtin_amdgcn_mfma_f32_16x16x32_bf16(A.v, b1f, a11, 0, 0, 0);
            } else {
                a00 = __builtin_amdgcn_mfma_f32_16x16x32_bf16(A.v, b0f, a00, 0, 0, 0);
                a10 = __builtin_amdgcn_mfma_f32_16x16x32_bf16(A.v, b1f, a10, 0, 0, 0);
            }
        }
        f32x4 A0 = a00 + a01, A1 = a10 + a11;

        const unsigned short xs0[4] = {x0.x, x0.y, x0.z, x0.w};
        const unsigned short xs1[4] = {x1.x, x1.y, x1.z, x1.w};
        float hreg[4] = {0.f, 0.f, 0.f, 0.f};
#pragma unroll
        for (int r = 0; r < 4; ++r) {
            float v0 = A0[r] + b2f(xs0[r]);
            float v1 = A1[r] + b2f(xs1[r]);
            float p0 = __shfl_xor(v0, 8, 64);
            float p1 = __shfl_xor(v1, 8, 64);
            float ipre = halfsel ? p0 : v0;
            float fpre = halfsel ? v0 : p0;
            float gpre = halfsel ? p1 : v1;
            float opre = halfsel ? v1 : p1;
            if (!halfsel) {
                float ig = 1.0f / (1.0f + __expf(-ipre));
                float fg = 1.0f / (1.0f + __expf(-fpre));
                float gg = tanhf(gpre);
                float og = 1.0f / (1.0f + __expf(-opre));
                float cnew = fg * creg[r] + ig * gg;
                float hnew = og * tanhf(cnew);
                creg[r] = cnew;
                hreg[r] = hnew;
                sPack[(b0 + r) * 8 + u] = __float2bfloat16(hnew);
            }
        }

        if (t == T_STEPS - 1) {
            // final step: emit last h row + final (h, c) rows; no sync needed
            if (!halfsel) {
#pragma unroll
                for (int r = 0; r < 4; ++r) {
                    int b = b0 + r;
                    out[(size_t)t * (BATCH * DH) + b * DH + jout] = hreg[r];
                    out[(size_t)T_STEPS * BATCH * DH + b * DH + jout] = hreg[r];
                    out[(size_t)T_STEPS * BATCH * DH + BATCH * DH + b * DH + jout] = creg[r];
                }
            }
        } else {
            __syncthreads();                     // sPack visible block-wide
            if (tid < 128)
                llc_store64(hout + pst_idx, *(const u64*)&sPack[tid * 4]);
            asm volatile("s_waitcnt vmcnt(0)" ::: "memory");  // h at LLC before flag
            __syncthreads();                     // all waves' h stores drained
            if (tid == 0) llc_store32(&flags[bk], (unsigned)(t + 2));
            // deferred out stores: issued AFTER the flag, drain during the poll
            if (!halfsel) {
#pragma unroll
                for (int r = 0; r < 4; ++r)
                    out[(size_t)t * (BATCH * DH) + (b0 + r) * DH + jout] = hreg[r];
            }
            // every wave polls all 128 flags (lane l -> flags[2l], flags[2l+1])
            const unsigned need = (unsigned)(t + 2);
            while (true) {
                u64 fv = llc_load64(f64 + l);
                if ((unsigned)fv >= need && (unsigned)(fv >> 32) >= need) break;
                __builtin_amdgcn_s_sleep(2);
            }
            asm volatile("" ::: "memory");       // compiler fence: no load hoisting
        }
    }
}

extern "C" void kernel_launch(void* const* d_in, const int* in_sizes, int n_in,
                              void* d_out, int out_size, void* d_ws, size_t ws_size,
                              hipStream_t stream) {
    const int*   xs  = (const int*)d_in[0];
    const float* emb = (const float*)d_in[1];
    const float* Wih = (const float*)d_in[2];
    const float* Whh = (const float*)d_in[3];
    const float* bih = (const float*)d_in[4];
    const float* bhh = (const float*)d_in[5];
    float* out = (float*)d_out;
    char*  ws  = (char*)d_ws;

    __hip_bfloat16* Wih_bf = (__hip_bfloat16*)(ws);                  //  4 MB
    __hip_bfloat16* Whh_bf = (__hip_bfloat16*)(ws + 4194304);        //  8 MB
    __hip_bfloat16* e_bf   = (__hip_bfloat16*)(ws + 12582912);       // 16 MB
    __hip_bfloat16* xgp    = (__hip_bfloat16*)(ws + 29360128);       // 128 MB
    __hip_bfloat16* hbuf   = (__hip_bfloat16*)(ws + 163577856);      // 384 KB (3 bufs)
    unsigned*       flags  = (unsigned*)(ws + 163971072);            // 512 B

    hipMemsetAsync(flags, 0, 512, stream);
    k_f32_to_bf16<<<1024, 256, 0, stream>>>(Wih, Wih_bf, 2097152 / 8);
    k_f32_to_bf16<<<2048, 256, 0, stream>>>(Whh, Whh_bf, 4194304 / 8);
    k_gather<<<4096, 256, 0, stream>>>(xs, emb, e_bf);
    k_gemm_xg<<<4096, 256, 0, stream>>>(e_bf, Wih_bf, bih, bhh, xgp);
    k_lstm<<<NBLK, 256, 0, stream>>>(xgp, Whh_bf, hbuf, out, flags);
}

// Round 3
// 2542.322 us; speedup vs baseline: 1.6924x; 1.6924x over previous
//
#include <hip/hip_runtime.h>
#include <hip/hip_bf16.h>
#include <cstdint>
#include <cstddef>

// LSTM encoder: T=256, B=64, VOCAB=32000, E=512, H=1024
#define T_STEPS 256
#define BATCH   64
#define DE      512
#define DH      1024
#define G4      4096   // 4*DH
#define NBLK    128    // recurrence blocks; each owns 8 hidden units

typedef short  bf16x8 __attribute__((ext_vector_type(8)));   // 8 bf16 = 4 VGPRs
typedef float  f32x4  __attribute__((ext_vector_type(4)));
typedef unsigned long long u64;

__device__ __forceinline__ unsigned short bf_bits(__hip_bfloat16 h) {
    union { __hip_bfloat16 h; unsigned short u; } x; x.h = h; return x.u;
}
__device__ __forceinline__ float b2f(unsigned short u) {
    union { float f; unsigned v; } x; x.v = ((unsigned)u) << 16; return x.f;
}

__device__ __forceinline__ void async_copy16(const void* gsrc, void* ldst) {
    __builtin_amdgcn_global_load_lds(
        (const __attribute__((address_space(1))) unsigned int*)gsrc,
        (__attribute__((address_space(3))) unsigned int*)ldst,
        16, 0, 0);
}

// relaxed agent-scope (LLC-coherent) accessors
__device__ __forceinline__ u64 llc_load64(const u64* p) {
    return __hip_atomic_load(p, __ATOMIC_RELAXED, __HIP_MEMORY_SCOPE_AGENT);
}
__device__ __forceinline__ void llc_store64(u64* p, u64 v) {
    __hip_atomic_store(p, v, __ATOMIC_RELAXED, __HIP_MEMORY_SCOPE_AGENT);
}
__device__ __forceinline__ unsigned llc_load32(const unsigned* p) {
    return __hip_atomic_load(p, __ATOMIC_RELAXED, __HIP_MEMORY_SCOPE_AGENT);
}
__device__ __forceinline__ void llc_store32(unsigned* p, unsigned v) {
    __hip_atomic_store(p, v, __ATOMIC_RELAXED, __HIP_MEMORY_SCOPE_AGENT);
}

// ---------------- fp32 -> bf16 convert (8 elems/thread) ----------------
__global__ void k_f32_to_bf16(const float* __restrict__ src,
                              __hip_bfloat16* __restrict__ dst, int n8) {
    int i = blockIdx.x * blockDim.x + threadIdx.x;
    if (i >= n8) return;
    const float4* s = (const float4*)src + (size_t)i * 2;
    float4 a = s[0], b = s[1];
    union { unsigned short u[8]; uint4 v; } o;
    o.u[0] = bf_bits(__float2bfloat16(a.x));
    o.u[1] = bf_bits(__float2bfloat16(a.y));
    o.u[2] = bf_bits(__float2bfloat16(a.z));
    o.u[3] = bf_bits(__float2bfloat16(a.w));
    o.u[4] = bf_bits(__float2bfloat16(b.x));
    o.u[5] = bf_bits(__float2bfloat16(b.y));
    o.u[6] = bf_bits(__float2bfloat16(b.z));
    o.u[7] = bf_bits(__float2bfloat16(b.w));
    *((uint4*)dst + i) = o.v;
}

// ---------------- embedding gather + bf16 convert ----------------
__global__ void k_gather(const int* __restrict__ xs, const float* __restrict__ emb,
                         __hip_bfloat16* __restrict__ e_bf) {
    int tid = blockIdx.x * 256 + threadIdx.x;
    int r = tid >> 6, ch = tid & 63;
    int v = xs[r];
    const float4* s = (const float4*)(emb + (size_t)v * DE + ch * 8);
    float4 a = s[0], b = s[1];
    union { unsigned short u[8]; uint4 v4; } o;
    o.u[0] = bf_bits(__float2bfloat16(a.x));
    o.u[1] = bf_bits(__float2bfloat16(a.y));
    o.u[2] = bf_bits(__float2bfloat16(a.z));
    o.u[3] = bf_bits(__float2bfloat16(a.w));
    o.u[4] = bf_bits(__float2bfloat16(b.x));
    o.u[5] = bf_bits(__float2bfloat16(b.y));
    o.u[6] = bf_bits(__float2bfloat16(b.z));
    o.u[7] = bf_bits(__float2bfloat16(b.w));
    *((uint4*)(e_bf + (size_t)r * DE) + ch) = o.v4;
}

// ---------------- x_gates GEMM -> permuted bf16 layout ----------------
// xgp[t][blk][gate][unit][batch] : (((t*128+blk)*4+g)*8+u)*64 + b
__global__ void k_gemm_xg(const __hip_bfloat16* __restrict__ A,   // [16384][512]
                          const __hip_bfloat16* __restrict__ Bt,  // [4096][512]
                          const float* __restrict__ bih, const float* __restrict__ bhh,
                          __hip_bfloat16* __restrict__ xgp) {
    __shared__ __align__(16) __hip_bfloat16 sA[128 * 32];
    __shared__ __align__(16) __hip_bfloat16 sB[128 * 32];
    const int bm = blockIdx.x >> 5;    // 128 M-tiles
    const int bn = blockIdx.x & 31;    // 32 N-tiles
    const int tid = threadIdx.x;
    const int l = tid & 63, w = tid >> 6;
    const int wm = w >> 1, wn = w & 1;
    const int lrow = l & 15, lq = l >> 4;

    f32x4 acc[4][4] = {};

    for (int kb = 0; kb < 512; kb += 32) {
#pragma unroll
        for (int q = 0; q < 2; ++q) {
            int c = q * 256 + tid;
            int row = c >> 2, seg = c & 3;
            async_copy16(A + (size_t)(bm * 128 + row) * 512 + kb + seg * 8, &sA[c * 8]);
            async_copy16(Bt + (size_t)(bn * 128 + row) * 512 + kb + seg * 8, &sB[c * 8]);
        }
        __syncthreads();
        bf16x8 af[4], bq[4];
#pragma unroll
        for (int mt = 0; mt < 4; ++mt)
            af[mt] = *(const bf16x8*)&sA[(wm * 64 + mt * 16 + lrow) * 32 + lq * 8];
#pragma unroll
        for (int nt = 0; nt < 4; ++nt)
            bq[nt] = *(const bf16x8*)&sB[(wn * 64 + nt * 16 + lrow) * 32 + lq * 8];
#pragma unroll
        for (int mt = 0; mt < 4; ++mt)
#pragma unroll
            for (int nt = 0; nt < 4; ++nt)
                acc[mt][nt] = __builtin_amdgcn_mfma_f32_16x16x32_bf16(
                    af[mt], bq[nt], acc[mt][nt], 0, 0, 0);
        __syncthreads();
    }

#pragma unroll
    for (int nt = 0; nt < 4; ++nt) {
        int n = bn * 128 + wn * 64 + nt * 16 + lrow;
        int g = n >> 10, j = n & 1023, blk = j >> 3, u = j & 7;
        float bias = bih[n] + bhh[n];
#pragma unroll
        for (int mt = 0; mt < 4; ++mt) {
#pragma unroll
            for (int r = 0; r < 4; ++r) {
                int m = bm * 128 + wm * 64 + mt * 16 + lq * 4 + r;
                int t = m >> 6, b = m & 63;
                xgp[(((size_t)(t * NBLK + blk) * 4 + g) * 8 + u) * 64 + b] =
                    __float2bfloat16(acc[mt][nt][r] + bias);
            }
        }
    }
}

// ---------------- persistent LSTM recurrence ----------------
// 128 blocks x 256 thr; block owns units j0=8*bk (32 gate rows).
// Whh slice LDS-resident (64 KB); c register-resident; h exchanged through the
// LLC via relaxed agent-scope 8B atomics, triple-buffered.
//
// hbuf layout: CHUNK-MAJOR (the 2236us-baseline layout). u64 index =
// chunk*512 + pairid*2 + half. Block bk's produced slice is the contiguous
// 1KB range [bk*128, bk*128+128) -> full-cacheline coalesced stores from one
// block (round-1's lane-major transpose scattered these 8B-per-line across
// blocks: +32MB HBM write traffic, 2x regression).
//
// Per-step protocol (vs 2236us baseline):
//  - FULL-K prefetch, forced: all 64 h loads issued, then an asm
//    s_waitcnt vmcnt(0) + memory clobber BEFORE the MFMA loop. Atomic loads
//    cannot sink past the memory-clobber asm, so the compiler must keep all
//    128 VGPRs of h live -> 1 LLC latency instead of the 8-deep pipeline's
//    ~4 serialized latencies. (Round-1 omitted the barrier; compiler sank the
//    loads back into the MFMA loop — VGPR_Count 108 proved it.)
//  - out[] HBM stores deferred until AFTER the flag store (their store-ack no
//    longer sits inside the pre-flag vmcnt(0)); they drain during the poll
//  - every wave polls all 128 flags itself (lane l checks pair 2l,2l+1 via one
//    8B LLC load) -> no post-poll __syncthreads
__global__ void __launch_bounds__(256, 1) k_lstm(
        const __hip_bfloat16* __restrict__ xgp,   // [256][128][4][8][64]
        const __hip_bfloat16* __restrict__ Whh,   // [4096][1024] row-major
        __hip_bfloat16* __restrict__ hbuf,        // 3 x 65536 elems, chunk-major
        float* __restrict__ out,
        unsigned* __restrict__ flags) {           // [128], zeroed per call
    __shared__ __hip_bfloat16 sW[32768];          // 64 KB: [nt2][kb32][q4][col16][8]
    __shared__ __align__(8) __hip_bfloat16 sPack[512];
    const int tid = threadIdx.x, l = tid & 63, w = tid >> 6;
    const int lrow = l & 15, lq = l >> 4;
    const int bk = blockIdx.x;

    // load Whh slice -> LDS, frag-contiguous
#pragma unroll
    for (int f = 0; f < 16; ++f) {
        int fi = f * 256 + tid;                  // frag index 0..4095
        int col = fi & 15, q = (fi >> 4) & 3, kb = (fi >> 6) & 31, nt = fi >> 11;
        int g = (nt * 16 + col) >> 3, u = col & 7;
        async_copy16(Whh + (size_t)(g * DH + bk * 8 + u) * DH + kb * 32 + q * 8,
                     &sW[fi * 8]);
    }
    // zero my slice of h buffer 0 through the LLC
    if (tid < 128)
        llc_store64((u64*)hbuf + bk * 128 + tid, 0ull);
    asm volatile("s_waitcnt vmcnt(0)" ::: "memory");
    __syncthreads();
    if (tid == 0) llc_store32(&flags[bk], 1u);
    if (tid < 128)
        while (llc_load32(&flags[tid]) < 1u) __builtin_amdgcn_s_sleep(2);
    __syncthreads();

    const int u = l & 7, halfsel = (l >> 3) & 1;
    const int b0 = w * 16 + lq * 4;
    const int aib = lq * 128 + w * 32 + lrow * 2;   // u64 index within a k-chunk
    const int jout = bk * 8 + u;                    // hidden-unit column in out
    const u64* f64 = (const u64*)flags;
    float creg[4] = {0.f, 0.f, 0.f, 0.f};

    for (int t = 0; t < T_STEPS; ++t) {
        const u64* hin  = (const u64*)hbuf + (size_t)(t % 3) * 16384;
        u64*       hout = (u64*)hbuf + (size_t)((t + 1) % 3) * 16384;

        // this step's xg (read-only, plain cached loads)
        const __hip_bfloat16* xgt = xgp + (size_t)t * (NBLK * 2048) + (size_t)bk * 2048;
        ushort4 x0 = *(const ushort4*)(xgt + (halfsel * 8 + u) * 64 + b0);
        ushort4 x1 = *(const ushort4*)(xgt + ((2 + halfsel) * 8 + u) * 64 + b0);

        // FULL-K prefetch: all 32 chunks (64 x 8B) in flight at once,
        // chunk-major addressing (stride 4KB between chunks).
        const u64* hl = hin + aib;
        u64 alo[32], ahi[32];
#pragma unroll
        for (int p = 0; p < 32; ++p) {
            alo[p] = llc_load64(hl + p * 512);
            ahi[p] = llc_load64(hl + p * 512 + 1);
        }
        // Hard fence: forces every load above to be issued (and completed)
        // before any MFMA below — defeats compiler load-sinking.
        asm volatile("s_waitcnt vmcnt(0)" ::: "memory");

        f32x4 a00 = {}, a01 = {}, a10 = {}, a11 = {};
#pragma unroll
        for (int kb = 0; kb < 32; ++kb) {
            union { u64 q[2]; bf16x8 v; } A;
            A.q[0] = alo[kb]; A.q[1] = ahi[kb];
            bf16x8 b0f = *(const bf16x8*)&sW[(kb * 4 + lq) * 128 + lrow * 8];
            bf16x8 b1f = *(const bf16x8*)&sW[16384 + (kb * 4 + lq) * 128 + lrow * 8];
            if (kb & 1) {
                a01 = __builtin_amdgcn_mfma_f32_16x16x32_bf16(A.v, b0f, a01, 0, 0, 0);
                a11 = __builtin_amdgcn_mfma_f32_16x16x32_bf16(A.v, b1f, a11, 0, 0, 0);
            } else {
                a00 = __builtin_amdgcn_mfma_f32_16x16x32_bf16(A.v, b0f, a00, 0, 0, 0);
                a10 = __builtin_amdgcn_mfma_f32_16x16x32_bf16(A.v, b1f, a10, 0, 0, 0);
            }
        }
        f32x4 A0 = a00 + a01, A1 = a10 + a11;

        const unsigned short xs0[4] = {x0.x, x0.y, x0.z, x0.w};
        const unsigned short xs1[4] = {x1.x, x1.y, x1.z, x1.w};
        float hreg[4] = {0.f, 0.f, 0.f, 0.f};
#pragma unroll
        for (int r = 0; r < 4; ++r) {
            float v0 = A0[r] + b2f(xs0[r]);
            float v1 = A1[r] + b2f(xs1[r]);
            float p0 = __shfl_xor(v0, 8, 64);
            float p1 = __shfl_xor(v1, 8, 64);
            float ipre = halfsel ? p0 : v0;
            float fpre = halfsel ? v0 : p0;
            float gpre = halfsel ? p1 : v1;
            float opre = halfsel ? v1 : p1;
            if (!halfsel) {
                float ig = 1.0f / (1.0f + __expf(-ipre));
                float fg = 1.0f / (1.0f + __expf(-fpre));
                float gg = tanhf(gpre);
                float og = 1.0f / (1.0f + __expf(-opre));
                float cnew = fg * creg[r] + ig * gg;
                float hnew = og * tanhf(cnew);
                creg[r] = cnew;
                hreg[r] = hnew;
                sPack[(b0 + r) * 8 + u] = __float2bfloat16(hnew);
            }
        }

        if (t == T_STEPS - 1) {
            // final step: emit last h row + final (h, c) rows; no sync needed
            if (!halfsel) {
#pragma unroll
                for (int r = 0; r < 4; ++r) {
                    int b = b0 + r;
                    out[(size_t)t * (BATCH * DH) + b * DH + jout] = hreg[r];
                    out[(size_t)T_STEPS * BATCH * DH + b * DH + jout] = hreg[r];
                    out[(size_t)T_STEPS * BATCH * DH + BATCH * DH + b * DH + jout] = creg[r];
                }
            }
        } else {
            __syncthreads();                     // sPack visible block-wide
            if (tid < 128)
                llc_store64(hout + bk * 128 + tid, *(const u64*)&sPack[tid * 4]);
            asm volatile("s_waitcnt vmcnt(0)" ::: "memory");  // h at LLC before flag
            __syncthreads();                     // all waves' h stores drained
            if (tid == 0) llc_store32(&flags[bk], (unsigned)(t + 2));
            // deferred out stores: issued AFTER the flag, drain during the poll
            if (!halfsel) {
#pragma unroll
                for (int r = 0; r < 4; ++r)
                    out[(size_t)t * (BATCH * DH) + (b0 + r) * DH + jout] = hreg[r];
            }
            // every wave polls all 128 flags (lane l -> flags[2l], flags[2l+1])
            const unsigned need = (unsigned)(t + 2);
            while (true) {
                u64 fv = llc_load64(f64 + l);
                if ((unsigned)fv >= need && (unsigned)(fv >> 32) >= need) break;
                __builtin_amdgcn_s_sleep(2);
            }
            asm volatile("" ::: "memory");       // compiler fence: no load hoisting
        }
    }
}

extern "C" void kernel_launch(void* const* d_in, const int* in_sizes, int n_in,
                              void* d_out, int out_size, void* d_ws, size_t ws_size,
                              hipStream_t stream) {
    const int*   xs  = (const int*)d_in[0];
    const float* emb = (const float*)d_in[1];
    const float* Wih = (const float*)d_in[2];
    const float* Whh = (const float*)d_in[3];
    const float* bih = (const float*)d_in[4];
    const float* bhh = (const float*)d_in[5];
    float* out = (float*)d_out;
    char*  ws  = (char*)d_ws;

    __hip_bfloat16* Wih_bf = (__hip_bfloat16*)(ws);                  //  4 MB
    __hip_bfloat16* Whh_bf = (__hip_bfloat16*)(ws + 4194304);        //  8 MB
    __hip_bfloat16* e_bf   = (__hip_bfloat16*)(ws + 12582912);       // 16 MB
    __hip_bfloat16* xgp    = (__hip_bfloat16*)(ws + 29360128);       // 128 MB
    __hip_bfloat16* hbuf   = (__hip_bfloat16*)(ws + 163577856);      // 384 KB (3 bufs)
    unsigned*       flags  = (unsigned*)(ws + 163971072);            // 512 B

    hipMemsetAsync(flags, 0, 512, stream);
    k_f32_to_bf16<<<1024, 256, 0, stream>>>(Wih, Wih_bf, 2097152 / 8);
    k_f32_to_bf16<<<2048, 256, 0, stream>>>(Whh, Whh_bf, 4194304 / 8);
    k_gather<<<4096, 256, 0, stream>>>(xs, emb, e_bf);
    k_gemm_xg<<<4096, 256, 0, stream>>>(e_bf, Wih_bf, bih, bhh, xgp);
    k_lstm<<<NBLK, 256, 0, stream>>>(xgp, Whh_bf, hbuf, out, flags);
}

// Round 4
// 2327.787 us; speedup vs baseline: 1.8484x; 1.0922x over previous
//
#include <hip/hip_runtime.h>
#include <hip/hip_bf16.h>
#include <cstdint>
#include <cstddef>

// LSTM encoder: T=256, B=64, VOCAB=32000, E=512, H=1024
#define T_STEPS 256
#define BATCH   64
#define DE      512
#define DH      1024
#define G4      4096   // 4*DH
#define NBLK    128    // recurrence blocks; each owns 8 hidden units

typedef short  bf16x8 __attribute__((ext_vector_type(8)));   // 8 bf16 = 4 VGPRs
typedef float  f32x4  __attribute__((ext_vector_type(4)));
typedef unsigned long long u64;

__device__ __forceinline__ unsigned short bf_bits(__hip_bfloat16 h) {
    union { __hip_bfloat16 h; unsigned short u; } x; x.h = h; return x.u;
}
__device__ __forceinline__ float b2f(unsigned short u) {
    union { float f; unsigned v; } x; x.v = ((unsigned)u) << 16; return x.f;
}

__device__ __forceinline__ void async_copy16(const void* gsrc, void* ldst) {
    __builtin_amdgcn_global_load_lds(
        (const __attribute__((address_space(1))) unsigned int*)gsrc,
        (__attribute__((address_space(3))) unsigned int*)ldst,
        16, 0, 0);
}

// relaxed agent-scope (LLC-coherent) accessors
__device__ __forceinline__ u64 llc_load64(const u64* p) {
    return __hip_atomic_load(p, __ATOMIC_RELAXED, __HIP_MEMORY_SCOPE_AGENT);
}
__device__ __forceinline__ void llc_store64(u64* p, u64 v) {
    __hip_atomic_store(p, v, __ATOMIC_RELAXED, __HIP_MEMORY_SCOPE_AGENT);
}
__device__ __forceinline__ unsigned llc_load32(const unsigned* p) {
    return __hip_atomic_load(p, __ATOMIC_RELAXED, __HIP_MEMORY_SCOPE_AGENT);
}
__device__ __forceinline__ void llc_store32(unsigned* p, unsigned v) {
    __hip_atomic_store(p, v, __ATOMIC_RELAXED, __HIP_MEMORY_SCOPE_AGENT);
}

// ---------------- fp32 -> bf16 convert (8 elems/thread) ----------------
__global__ void k_f32_to_bf16(const float* __restrict__ src,
                              __hip_bfloat16* __restrict__ dst, int n8) {
    int i = blockIdx.x * blockDim.x + threadIdx.x;
    if (i >= n8) return;
    const float4* s = (const float4*)src + (size_t)i * 2;
    float4 a = s[0], b = s[1];
    union { unsigned short u[8]; uint4 v; } o;
    o.u[0] = bf_bits(__float2bfloat16(a.x));
    o.u[1] = bf_bits(__float2bfloat16(a.y));
    o.u[2] = bf_bits(__float2bfloat16(a.z));
    o.u[3] = bf_bits(__float2bfloat16(a.w));
    o.u[4] = bf_bits(__float2bfloat16(b.x));
    o.u[5] = bf_bits(__float2bfloat16(b.y));
    o.u[6] = bf_bits(__float2bfloat16(b.z));
    o.u[7] = bf_bits(__float2bfloat16(b.w));
    *((uint4*)dst + i) = o.v;
}

// ---------------- embedding gather + bf16 convert ----------------
__global__ void k_gather(const int* __restrict__ xs, const float* __restrict__ emb,
                         __hip_bfloat16* __restrict__ e_bf) {
    int tid = blockIdx.x * 256 + threadIdx.x;
    int r = tid >> 6, ch = tid & 63;
    int v = xs[r];
    const float4* s = (const float4*)(emb + (size_t)v * DE + ch * 8);
    float4 a = s[0], b = s[1];
    union { unsigned short u[8]; uint4 v4; } o;
    o.u[0] = bf_bits(__float2bfloat16(a.x));
    o.u[1] = bf_bits(__float2bfloat16(a.y));
    o.u[2] = bf_bits(__float2bfloat16(a.z));
    o.u[3] = bf_bits(__float2bfloat16(a.w));
    o.u[4] = bf_bits(__float2bfloat16(b.x));
    o.u[5] = bf_bits(__float2bfloat16(b.y));
    o.u[6] = bf_bits(__float2bfloat16(b.z));
    o.u[7] = bf_bits(__float2bfloat16(b.w));
    *((uint4*)(e_bf + (size_t)r * DE) + ch) = o.v4;
}

// ---------------- x_gates GEMM -> permuted bf16 layout ----------------
// xgp[t][blk][gate][unit][batch] : (((t*128+blk)*4+g)*8+u)*64 + b
__global__ void k_gemm_xg(const __hip_bfloat16* __restrict__ A,   // [16384][512]
                          const __hip_bfloat16* __restrict__ Bt,  // [4096][512]
                          const float* __restrict__ bih, const float* __restrict__ bhh,
                          __hip_bfloat16* __restrict__ xgp) {
    __shared__ __align__(16) __hip_bfloat16 sA[128 * 32];
    __shared__ __align__(16) __hip_bfloat16 sB[128 * 32];
    const int bm = blockIdx.x >> 5;    // 128 M-tiles
    const int bn = blockIdx.x & 31;    // 32 N-tiles
    const int tid = threadIdx.x;
    const int l = tid & 63, w = tid >> 6;
    const int wm = w >> 1, wn = w & 1;
    const int lrow = l & 15, lq = l >> 4;

    f32x4 acc[4][4] = {};

    for (int kb = 0; kb < 512; kb += 32) {
#pragma unroll
        for (int q = 0; q < 2; ++q) {
            int c = q * 256 + tid;
            int row = c >> 2, seg = c & 3;
            async_copy16(A + (size_t)(bm * 128 + row) * 512 + kb + seg * 8, &sA[c * 8]);
            async_copy16(Bt + (size_t)(bn * 128 + row) * 512 + kb + seg * 8, &sB[c * 8]);
        }
        __syncthreads();
        bf16x8 af[4], bq[4];
#pragma unroll
        for (int mt = 0; mt < 4; ++mt)
            af[mt] = *(const bf16x8*)&sA[(wm * 64 + mt * 16 + lrow) * 32 + lq * 8];
#pragma unroll
        for (int nt = 0; nt < 4; ++nt)
            bq[nt] = *(const bf16x8*)&sB[(wn * 64 + nt * 16 + lrow) * 32 + lq * 8];
#pragma unroll
        for (int mt = 0; mt < 4; ++mt)
#pragma unroll
            for (int nt = 0; nt < 4; ++nt)
                acc[mt][nt] = __builtin_amdgcn_mfma_f32_16x16x32_bf16(
                    af[mt], bq[nt], acc[mt][nt], 0, 0, 0);
        __syncthreads();
    }

#pragma unroll
    for (int nt = 0; nt < 4; ++nt) {
        int n = bn * 128 + wn * 64 + nt * 16 + lrow;
        int g = n >> 10, j = n & 1023, blk = j >> 3, u = j & 7;
        float bias = bih[n] + bhh[n];
#pragma unroll
        for (int mt = 0; mt < 4; ++mt) {
#pragma unroll
            for (int r = 0; r < 4; ++r) {
                int m = bm * 128 + wm * 64 + mt * 16 + lq * 4 + r;
                int t = m >> 6, b = m & 63;
                xgp[(((size_t)(t * NBLK + blk) * 4 + g) * 8 + u) * 64 + b] =
                    __float2bfloat16(acc[mt][nt][r] + bias);
            }
        }
    }
}

// ---------------- persistent LSTM recurrence ----------------
// 128 blocks x 256 thr; block owns units j0=8*bk (32 gate rows).
// Whh slice LDS-resident (64 KB); c register-resident; h exchanged through the
// LLC via relaxed agent-scope 8B atomics, triple-buffered; barrier =
// per-block flag array.
//
// EXACT 2025us-baseline protocol (out stores inside the pre-flag drain,
// tid<128 poll + post-poll barrier, chunk-major hbuf). ONE change vs
// baseline: the h-load software pipeline is 16-deep instead of 8-deep
// (alo/ahi[16], rotate kb&15, prefetch kb+16). Under L_llc ~= 1500-2000cy
// the h-chain cost drops 32*(L/8) -> 32*(L/16), ~ -4000 cy/step.
// Tripwire: VGPR_Count must rise to ~120; if it stays ~88-108 the compiler
// defeated the deeper pipeline again.
__global__ void __launch_bounds__(256) k_lstm(
        const __hip_bfloat16* __restrict__ xgp,   // [256][128][4][8][64]
        const __hip_bfloat16* __restrict__ Whh,   // [4096][1024] row-major
        __hip_bfloat16* __restrict__ hbuf,        // 3 x 65536 elems, chunk-major
        float* __restrict__ out,
        unsigned* __restrict__ flags) {           // [128], zeroed per call
    __shared__ __hip_bfloat16 sW[32768];          // 64 KB: [nt2][kb32][q4][col16][8]
    __shared__ __align__(8) __hip_bfloat16 sPack[512];
    const int tid = threadIdx.x, l = tid & 63, w = tid >> 6;
    const int lrow = l & 15, lq = l >> 4;
    const int bk = blockIdx.x;

    // load Whh slice -> LDS, frag-contiguous
#pragma unroll
    for (int f = 0; f < 16; ++f) {
        int fi = f * 256 + tid;                  // frag index 0..4095
        int col = fi & 15, q = (fi >> 4) & 3, kb = (fi >> 6) & 31, nt = fi >> 11;
        int g = (nt * 16 + col) >> 3, u = col & 7;
        async_copy16(Whh + (size_t)(g * DH + bk * 8 + u) * DH + kb * 32 + q * 8,
                     &sW[fi * 8]);
    }
    // zero my slice of h buffer 0 through the LLC
    if (tid < 128)
        llc_store64((u64*)hbuf + bk * 128 + tid, 0ull);
    asm volatile("s_waitcnt vmcnt(0)" ::: "memory");
    __syncthreads();
    if (tid == 0) llc_store32(&flags[bk], 1u);
    if (tid < 128)
        while (llc_load32(&flags[tid]) < 1u) __builtin_amdgcn_s_sleep(2);
    __syncthreads();

    const int u = l & 7, halfsel = (l >> 3) & 1;
    const int b0 = w * 16 + lq * 4;
    const int aib = lq * 128 + w * 32 + lrow * 2;   // u64 index within a k-chunk
    float creg[4] = {0.f, 0.f, 0.f, 0.f};

    for (int t = 0; t < T_STEPS; ++t) {
        const u64* hin  = (const u64*)hbuf + (size_t)(t % 3) * 16384;
        u64*       hout = (u64*)hbuf + (size_t)((t + 1) % 3) * 16384;

        // this step's xg (read-only, plain cached loads)
        const __hip_bfloat16* xgt = xgp + (size_t)t * (NBLK * 2048) + (size_t)bk * 2048;
        ushort4 x0 = *(const ushort4*)(xgt + (halfsel * 8 + u) * 64 + b0);
        ushort4 x1 = *(const ushort4*)(xgt + ((2 + halfsel) * 8 + u) * 64 + b0);

        // K-loop: h A-frags from LLC (16-deep pipeline), Whh B-frags from LDS
        u64 alo[16], ahi[16];
#pragma unroll
        for (int p = 0; p < 16; ++p) {
            alo[p] = llc_load64(hin + p * 512 + aib);
            ahi[p] = llc_load64(hin + p * 512 + aib + 1);
        }
        f32x4 a00 = {}, a01 = {}, a10 = {}, a11 = {};
#pragma unroll
        for (int kb = 0; kb < 32; ++kb) {
            union { u64 q[2]; bf16x8 v; } A;
            A.q[0] = alo[kb & 15]; A.q[1] = ahi[kb & 15];
            bf16x8 b0f = *(const bf16x8*)&sW[(kb * 4 + lq) * 128 + lrow * 8];
            bf16x8 b1f = *(const bf16x8*)&sW[16384 + (kb * 4 + lq) * 128 + lrow * 8];
            if (kb & 1) {
                a01 = __builtin_amdgcn_mfma_f32_16x16x32_bf16(A.v, b0f, a01, 0, 0, 0);
                a11 = __builtin_amdgcn_mfma_f32_16x16x32_bf16(A.v, b1f, a11, 0, 0, 0);
            } else {
                a00 = __builtin_amdgcn_mfma_f32_16x16x32_bf16(A.v, b0f, a00, 0, 0, 0);
                a10 = __builtin_amdgcn_mfma_f32_16x16x32_bf16(A.v, b1f, a10, 0, 0, 0);
            }
            if (kb + 16 < 32) {
                alo[kb & 15] = llc_load64(hin + (kb + 16) * 512 + aib);
                ahi[kb & 15] = llc_load64(hin + (kb + 16) * 512 + aib + 1);
            }
        }
        f32x4 A0 = a00 + a01, A1 = a10 + a11;

        const unsigned short xs0[4] = {x0.x, x0.y, x0.z, x0.w};
        const unsigned short xs1[4] = {x1.x, x1.y, x1.z, x1.w};
#pragma unroll
        for (int r = 0; r < 4; ++r) {
            float v0 = A0[r] + b2f(xs0[r]);
            float v1 = A1[r] + b2f(xs1[r]);
            float p0 = __shfl_xor(v0, 8, 64);
            float p1 = __shfl_xor(v1, 8, 64);
            float ipre = halfsel ? p0 : v0;
            float fpre = halfsel ? v0 : p0;
            float gpre = halfsel ? p1 : v1;
            float opre = halfsel ? v1 : p1;
            if (!halfsel) {
                float ig = 1.0f / (1.0f + __expf(-ipre));
                float fg = 1.0f / (1.0f + __expf(-fpre));
                float gg = tanhf(gpre);
                float og = 1.0f / (1.0f + __expf(-opre));
                float cnew = fg * creg[r] + ig * gg;
                float hnew = og * tanhf(cnew);
                creg[r] = cnew;
                int b = b0 + r;
                int j = bk * 8 + u;
                sPack[b * 8 + u] = __float2bfloat16(hnew);
                out[(size_t)t * (BATCH * DH) + b * DH + j] = hnew;
                if (t == T_STEPS - 1) {
                    out[(size_t)T_STEPS * BATCH * DH + b * DH + j] = hnew;
                    out[(size_t)T_STEPS * BATCH * DH + BATCH * DH + b * DH + j] = cnew;
                }
            }
        }
        __syncthreads();                         // sPack visible block-wide
        if (tid < 128)
            llc_store64(hout + bk * 128 + tid, *(const u64*)&sPack[tid * 4]);
        if (t < T_STEPS - 1) {
            asm volatile("s_waitcnt vmcnt(0)" ::: "memory");  // h at LLC before flag
            __syncthreads();                     // all waves drained
            if (tid == 0) llc_store32(&flags[bk], (unsigned)(t + 2));
            if (tid < 128)
                while (llc_load32(&flags[tid]) < (unsigned)(t + 2))
                    __builtin_amdgcn_s_sleep(2);
            __syncthreads();
        }
    }
}

extern "C" void kernel_launch(void* const* d_in, const int* in_sizes, int n_in,
                              void* d_out, int out_size, void* d_ws, size_t ws_size,
                              hipStream_t stream) {
    const int*   xs  = (const int*)d_in[0];
    const float* emb = (const float*)d_in[1];
    const float* Wih = (const float*)d_in[2];
    const float* Whh = (const float*)d_in[3];
    const float* bih = (const float*)d_in[4];
    const float* bhh = (const float*)d_in[5];
    float* out = (float*)d_out;
    char*  ws  = (char*)d_ws;

    __hip_bfloat16* Wih_bf = (__hip_bfloat16*)(ws);                  //  4 MB
    __hip_bfloat16* Whh_bf = (__hip_bfloat16*)(ws + 4194304);        //  8 MB
    __hip_bfloat16* e_bf   = (__hip_bfloat16*)(ws + 12582912);       // 16 MB
    __hip_bfloat16* xgp    = (__hip_bfloat16*)(ws + 29360128);       // 128 MB
    __hip_bfloat16* hbuf   = (__hip_bfloat16*)(ws + 163577856);      // 384 KB (3 bufs)
    unsigned*       flags  = (unsigned*)(ws + 163971072);            // 512 B

    hipMemsetAsync(flags, 0, 512, stream);
    k_f32_to_bf16<<<1024, 256, 0, stream>>>(Wih, Wih_bf, 2097152 / 8);
    k_f32_to_bf16<<<2048, 256, 0, stream>>>(Whh, Whh_bf, 4194304 / 8);
    k_gather<<<4096, 256, 0, stream>>>(xs, emb, e_bf);
    k_gemm_xg<<<4096, 256, 0, stream>>>(e_bf, Wih_bf, bih, bhh, xgp);
    k_lstm<<<NBLK, 256, 0, stream>>>(xgp, Whh_bf, hbuf, out, flags);
}

// Round 5
// 2284.647 us; speedup vs baseline: 1.8833x; 1.0189x over previous
//
#include <hip/hip_runtime.h>
#include <hip/hip_bf16.h>
#include <cstdint>
#include <cstddef>

// LSTM encoder: T=256, B=64, VOCAB=32000, E=512, H=1024
#define T_STEPS 256
#define BATCH   64
#define DE      512
#define DH      1024
#define G4      4096   // 4*DH
#define NBLK    128    // recurrence blocks; each owns 8 hidden units

typedef short  bf16x8 __attribute__((ext_vector_type(8)));   // 8 bf16 = 4 VGPRs
typedef float  f32x4  __attribute__((ext_vector_type(4)));
typedef unsigned long long u64;

__device__ __forceinline__ unsigned short bf_bits(__hip_bfloat16 h) {
    union { __hip_bfloat16 h; unsigned short u; } x; x.h = h; return x.u;
}
__device__ __forceinline__ float b2f(unsigned short u) {
    union { float f; unsigned v; } x; x.v = ((unsigned)u) << 16; return x.f;
}

__device__ __forceinline__ void async_copy16(const void* gsrc, void* ldst) {
    __builtin_amdgcn_global_load_lds(
        (const __attribute__((address_space(1))) unsigned int*)gsrc,
        (__attribute__((address_space(3))) unsigned int*)ldst,
        16, 0, 0);
}

// relaxed agent-scope (LLC-coherent) accessors
__device__ __forceinline__ u64 llc_load64(const u64* p) {
    return __hip_atomic_load(p, __ATOMIC_RELAXED, __HIP_MEMORY_SCOPE_AGENT);
}
__device__ __forceinline__ void llc_store64(u64* p, u64 v) {
    __hip_atomic_store(p, v, __ATOMIC_RELAXED, __HIP_MEMORY_SCOPE_AGENT);
}
__device__ __forceinline__ unsigned llc_load32(const unsigned* p) {
    return __hip_atomic_load(p, __ATOMIC_RELAXED, __HIP_MEMORY_SCOPE_AGENT);
}
__device__ __forceinline__ void llc_store32(unsigned* p, unsigned v) {
    __hip_atomic_store(p, v, __ATOMIC_RELAXED, __HIP_MEMORY_SCOPE_AGENT);
}

// ---------------- fp32 -> bf16 convert (8 elems/thread) ----------------
__global__ void k_f32_to_bf16(const float* __restrict__ src,
                              __hip_bfloat16* __restrict__ dst, int n8) {
    int i = blockIdx.x * blockDim.x + threadIdx.x;
    if (i >= n8) return;
    const float4* s = (const float4*)src + (size_t)i * 2;
    float4 a = s[0], b = s[1];
    union { unsigned short u[8]; uint4 v; } o;
    o.u[0] = bf_bits(__float2bfloat16(a.x));
    o.u[1] = bf_bits(__float2bfloat16(a.y));
    o.u[2] = bf_bits(__float2bfloat16(a.z));
    o.u[3] = bf_bits(__float2bfloat16(a.w));
    o.u[4] = bf_bits(__float2bfloat16(b.x));
    o.u[5] = bf_bits(__float2bfloat16(b.y));
    o.u[6] = bf_bits(__float2bfloat16(b.z));
    o.u[7] = bf_bits(__float2bfloat16(b.w));
    *((uint4*)dst + i) = o.v;
}

// ---------------- embedding gather + bf16 convert ----------------
__global__ void k_gather(const int* __restrict__ xs, const float* __restrict__ emb,
                         __hip_bfloat16* __restrict__ e_bf) {
    int tid = blockIdx.x * 256 + threadIdx.x;
    int r = tid >> 6, ch = tid & 63;
    int v = xs[r];
    const float4* s = (const float4*)(emb + (size_t)v * DE + ch * 8);
    float4 a = s[0], b = s[1];
    union { unsigned short u[8]; uint4 v4; } o;
    o.u[0] = bf_bits(__float2bfloat16(a.x));
    o.u[1] = bf_bits(__float2bfloat16(a.y));
    o.u[2] = bf_bits(__float2bfloat16(a.z));
    o.u[3] = bf_bits(__float2bfloat16(a.w));
    o.u[4] = bf_bits(__float2bfloat16(b.x));
    o.u[5] = bf_bits(__float2bfloat16(b.y));
    o.u[6] = bf_bits(__float2bfloat16(b.z));
    o.u[7] = bf_bits(__float2bfloat16(b.w));
    *((uint4*)(e_bf + (size_t)r * DE) + ch) = o.v4;
}

// ---------------- x_gates GEMM -> permuted bf16 layout ----------------
// xgp[t][blk][gate][unit][batch] : (((t*128+blk)*4+g)*8+u)*64 + b
__global__ void k_gemm_xg(const __hip_bfloat16* __restrict__ A,   // [16384][512]
                          const __hip_bfloat16* __restrict__ Bt,  // [4096][512]
                          const float* __restrict__ bih, const float* __restrict__ bhh,
                          __hip_bfloat16* __restrict__ xgp) {
    __shared__ __align__(16) __hip_bfloat16 sA[128 * 32];
    __shared__ __align__(16) __hip_bfloat16 sB[128 * 32];
    const int bm = blockIdx.x >> 5;    // 128 M-tiles
    const int bn = blockIdx.x & 31;    // 32 N-tiles
    const int tid = threadIdx.x;
    const int l = tid & 63, w = tid >> 6;
    const int wm = w >> 1, wn = w & 1;
    const int lrow = l & 15, lq = l >> 4;

    f32x4 acc[4][4] = {};

    for (int kb = 0; kb < 512; kb += 32) {
#pragma unroll
        for (int q = 0; q < 2; ++q) {
            int c = q * 256 + tid;
            int row = c >> 2, seg = c & 3;
            async_copy16(A + (size_t)(bm * 128 + row) * 512 + kb + seg * 8, &sA[c * 8]);
            async_copy16(Bt + (size_t)(bn * 128 + row) * 512 + kb + seg * 8, &sB[c * 8]);
        }
        __syncthreads();
        bf16x8 af[4], bq[4];
#pragma unroll
        for (int mt = 0; mt < 4; ++mt)
            af[mt] = *(const bf16x8*)&sA[(wm * 64 + mt * 16 + lrow) * 32 + lq * 8];
#pragma unroll
        for (int nt = 0; nt < 4; ++nt)
            bq[nt] = *(const bf16x8*)&sB[(wn * 64 + nt * 16 + lrow) * 32 + lq * 8];
#pragma unroll
        for (int mt = 0; mt < 4; ++mt)
#pragma unroll
            for (int nt = 0; nt < 4; ++nt)
                acc[mt][nt] = __builtin_amdgcn_mfma_f32_16x16x32_bf16(
                    af[mt], bq[nt], acc[mt][nt], 0, 0, 0);
        __syncthreads();
    }

#pragma unroll
    for (int nt = 0; nt < 4; ++nt) {
        int n = bn * 128 + wn * 64 + nt * 16 + lrow;
        int g = n >> 10, j = n & 1023, blk = j >> 3, u = j & 7;
        float bias = bih[n] + bhh[n];
#pragma unroll
        for (int mt = 0; mt < 4; ++mt) {
#pragma unroll
            for (int r = 0; r < 4; ++r) {
                int m = bm * 128 + wm * 64 + mt * 16 + lq * 4 + r;
                int t = m >> 6, b = m & 63;
                xgp[(((size_t)(t * NBLK + blk) * 4 + g) * 8 + u) * 64 + b] =
                    __float2bfloat16(acc[mt][nt][r] + bias);
            }
        }
    }
}

// ---------------- persistent LSTM recurrence ----------------
// 128 blocks x 256 thr; block owns units j0=8*bk (32 gate rows).
// Whh slice LDS-resident (64 KB); c register-resident; h exchanged through the
// LLC via relaxed agent-scope 8B atomics, triple-buffered; barrier =
// per-block flag array. EXACT 2025us-baseline protocol.
//
// ONE change vs baseline: the 32 h A-fragments (each 16B, alo/ahi adjacent)
// are loaded with 32 INLINE-ASM global_load_dwordx4 issued back-to-back,
// then a single s_waitcnt vmcnt(0) + sched_barrier before the MFMA loop.
// Rationale: rounds 3/4 proved hipcc re-batches source-level prefetch
// (inserts its own waitcnt+spill between atomic loads to cap VMEM register
// pressure -> ~4 serialized LLC latencies). asm volatile loads cannot be
// reordered/batched and their "=v" outputs must stay in registers -> all
// 32 loads in flight simultaneously -> ONE LLC latency per step.
// Tripwire: VGPR_Count must jump to ~200+; if not, this mechanism is wrong.
__global__ void __launch_bounds__(256, 1) k_lstm(
        const __hip_bfloat16* __restrict__ xgp,   // [256][128][4][8][64]
        const __hip_bfloat16* __restrict__ Whh,   // [4096][1024] row-major
        __hip_bfloat16* __restrict__ hbuf,        // 3 x 65536 elems, chunk-major
        float* __restrict__ out,
        unsigned* __restrict__ flags) {           // [128], zeroed per call
    __shared__ __hip_bfloat16 sW[32768];          // 64 KB: [nt2][kb32][q4][col16][8]
    __shared__ __align__(8) __hip_bfloat16 sPack[512];
    const int tid = threadIdx.x, l = tid & 63, w = tid >> 6;
    const int lrow = l & 15, lq = l >> 4;
    const int bk = blockIdx.x;

    // load Whh slice -> LDS, frag-contiguous
#pragma unroll
    for (int f = 0; f < 16; ++f) {
        int fi = f * 256 + tid;                  // frag index 0..4095
        int col = fi & 15, q = (fi >> 4) & 3, kb = (fi >> 6) & 31, nt = fi >> 11;
        int g = (nt * 16 + col) >> 3, u = col & 7;
        async_copy16(Whh + (size_t)(g * DH + bk * 8 + u) * DH + kb * 32 + q * 8,
                     &sW[fi * 8]);
    }
    // zero my slice of h buffer 0 through the LLC
    if (tid < 128)
        llc_store64((u64*)hbuf + bk * 128 + tid, 0ull);
    asm volatile("s_waitcnt vmcnt(0)" ::: "memory");
    __syncthreads();
    if (tid == 0) llc_store32(&flags[bk], 1u);
    if (tid < 128)
        while (llc_load32(&flags[tid]) < 1u) __builtin_amdgcn_s_sleep(2);
    __syncthreads();

    const int u = l & 7, halfsel = (l >> 3) & 1;
    const int b0 = w * 16 + lq * 4;
    const int aib = lq * 128 + w * 32 + lrow * 2;   // u64 index within a k-chunk
    const unsigned aib8 = (unsigned)(aib * 8);      // byte offset within a chunk
    float creg[4] = {0.f, 0.f, 0.f, 0.f};

    for (int t = 0; t < T_STEPS; ++t) {
        const u64* hin  = (const u64*)hbuf + (size_t)(t % 3) * 16384;
        u64*       hout = (u64*)hbuf + (size_t)((t + 1) % 3) * 16384;

        // this step's xg (read-only, plain cached loads)
        const __hip_bfloat16* xgt = xgp + (size_t)t * (NBLK * 2048) + (size_t)bk * 2048;
        ushort4 x0 = *(const ushort4*)(xgt + (halfsel * 8 + u) * 64 + b0);
        ushort4 x1 = *(const ushort4*)(xgt + ((2 + halfsel) * 8 + u) * 64 + b0);

        // Full-K h prefetch via inline-asm loads: 32 x global_load_dwordx4
        // (16B A-fragment per chunk; alo/ahi adjacent, 16B-aligned), all in
        // flight at once (<= 63 vmcnt cap), ONE wait. sc0 sc1 = coherent read
        // (>= agent scope: bypasses stale L1/L2 copies, serves from LLC).
        bf16x8 afr[32];
#pragma unroll
        for (int p = 0; p < 32; ++p) {
            unsigned voff = aib8 + (unsigned)(p * 4096);
            asm volatile("global_load_dwordx4 %0, %1, %2 sc0 sc1"
                         : "=v"(afr[p])
                         : "v"(voff), "s"(hin));
        }
        asm volatile("s_waitcnt vmcnt(0)" ::: "memory");
        __builtin_amdgcn_sched_barrier(0);       // rule #18: keep MFMAs below

        f32x4 a00 = {}, a01 = {}, a10 = {}, a11 = {};
#pragma unroll
        for (int kb = 0; kb < 32; ++kb) {
            bf16x8 b0f = *(const bf16x8*)&sW[(kb * 4 + lq) * 128 + lrow * 8];
            bf16x8 b1f = *(const bf16x8*)&sW[16384 + (kb * 4 + lq) * 128 + lrow * 8];
            if (kb & 1) {
                a01 = __builtin_amdgcn_mfma_f32_16x16x32_bf16(afr[kb], b0f, a01, 0, 0, 0);
                a11 = __builtin_amdgcn_mfma_f32_16x16x32_bf16(afr[kb], b1f, a11, 0, 0, 0);
            } else {
                a00 = __builtin_amdgcn_mfma_f32_16x16x32_bf16(afr[kb], b0f, a00, 0, 0, 0);
                a10 = __builtin_amdgcn_mfma_f32_16x16x32_bf16(afr[kb], b1f, a10, 0, 0, 0);
            }
        }
        f32x4 A0 = a00 + a01, A1 = a10 + a11;

        const unsigned short xs0[4] = {x0.x, x0.y, x0.z, x0.w};
        const unsigned short xs1[4] = {x1.x, x1.y, x1.z, x1.w};
#pragma unroll
        for (int r = 0; r < 4; ++r) {
            float v0 = A0[r] + b2f(xs0[r]);
            float v1 = A1[r] + b2f(xs1[r]);
            float p0 = __shfl_xor(v0, 8, 64);
            float p1 = __shfl_xor(v1, 8, 64);
            float ipre = halfsel ? p0 : v0;
            float fpre = halfsel ? v0 : p0;
            float gpre = halfsel ? p1 : v1;
            float opre = halfsel ? v1 : p1;
            if (!halfsel) {
                float ig = 1.0f / (1.0f + __expf(-ipre));
                float fg = 1.0f / (1.0f + __expf(-fpre));
                float gg = tanhf(gpre);
                float og = 1.0f / (1.0f + __expf(-opre));
                float cnew = fg * creg[r] + ig * gg;
                float hnew = og * tanhf(cnew);
                creg[r] = cnew;
                int b = b0 + r;
                int j = bk * 8 + u;
                sPack[b * 8 + u] = __float2bfloat16(hnew);
                out[(size_t)t * (BATCH * DH) + b * DH + j] = hnew;
                if (t == T_STEPS - 1) {
                    out[(size_t)T_STEPS * BATCH * DH + b * DH + j] = hnew;
                    out[(size_t)T_STEPS * BATCH * DH + BATCH * DH + b * DH + j] = cnew;
                }
            }
        }
        __syncthreads();                         // sPack visible block-wide
        if (tid < 128)
            llc_store64(hout + bk * 128 + tid, *(const u64*)&sPack[tid * 4]);
        if (t < T_STEPS - 1) {
            asm volatile("s_waitcnt vmcnt(0)" ::: "memory");  // h at LLC before flag
            __syncthreads();                     // all waves drained
            if (tid == 0) llc_store32(&flags[bk], (unsigned)(t + 2));
            if (tid < 128)
                while (llc_load32(&flags[tid]) < (unsigned)(t + 2))
                    __builtin_amdgcn_s_sleep(2);
            __syncthreads();
        }
    }
}

extern "C" void kernel_launch(void* const* d_in, const int* in_sizes, int n_in,
                              void* d_out, int out_size, void* d_ws, size_t ws_size,
                              hipStream_t stream) {
    const int*   xs  = (const int*)d_in[0];
    const float* emb = (const float*)d_in[1];
    const float* Wih = (const float*)d_in[2];
    const float* Whh = (const float*)d_in[3];
    const float* bih = (const float*)d_in[4];
    const float* bhh = (const float*)d_in[5];
    float* out = (float*)d_out;
    char*  ws  = (char*)d_ws;

    __hip_bfloat16* Wih_bf = (__hip_bfloat16*)(ws);                  //  4 MB
    __hip_bfloat16* Whh_bf = (__hip_bfloat16*)(ws + 4194304);        //  8 MB
    __hip_bfloat16* e_bf   = (__hip_bfloat16*)(ws + 12582912);       // 16 MB
    __hip_bfloat16* xgp    = (__hip_bfloat16*)(ws + 29360128);       // 128 MB
    __hip_bfloat16* hbuf   = (__hip_bfloat16*)(ws + 163577856);      // 384 KB (3 bufs)
    unsigned*       flags  = (unsigned*)(ws + 163971072);            // 512 B

    hipMemsetAsync(flags, 0, 512, stream);
    k_f32_to_bf16<<<1024, 256, 0, stream>>>(Wih, Wih_bf, 2097152 / 8);
    k_f32_to_bf16<<<2048, 256, 0, stream>>>(Whh, Whh_bf, 4194304 / 8);
    k_gather<<<4096, 256, 0, stream>>>(xs, emb, e_bf);
    k_gemm_xg<<<4096, 256, 0, stream>>>(e_bf, Wih_bf, bih, bhh, xgp);
    k_lstm<<<NBLK, 256, 0, stream>>>(xgp, Whh_bf, hbuf, out, flags);
}

// Round 6
// 2265.378 us; speedup vs baseline: 1.8993x; 1.0085x over previous
//
#include <hip/hip_runtime.h>
#include <hip/hip_bf16.h>
#include <cstdint>
#include <cstddef>

// LSTM encoder: T=256, B=64, VOCAB=32000, E=512, H=1024
#define T_STEPS 256
#define BATCH   64
#define DE      512
#define DH      1024
#define G4      4096   // 4*DH
#define NBLK    128    // recurrence blocks; each owns 8 hidden units

typedef short  bf16x8 __attribute__((ext_vector_type(8)));   // 8 bf16 = 4 VGPRs
typedef float  f32x4  __attribute__((ext_vector_type(4)));
typedef unsigned int u32x4 __attribute__((ext_vector_type(4)));
typedef unsigned long long u64;

__device__ __forceinline__ unsigned short bf_bits(__hip_bfloat16 h) {
    union { __hip_bfloat16 h; unsigned short u; } x; x.h = h; return x.u;
}
__device__ __forceinline__ float b2f(unsigned short u) {
    union { float f; unsigned v; } x; x.v = ((unsigned)u) << 16; return x.f;
}

__device__ __forceinline__ void async_copy16(const void* gsrc, void* ldst) {
    __builtin_amdgcn_global_load_lds(
        (const __attribute__((address_space(1))) unsigned int*)gsrc,
        (__attribute__((address_space(3))) unsigned int*)ldst,
        16, 0, 0);
}

// relaxed agent-scope (LLC-coherent) accessors
__device__ __forceinline__ u64 llc_load64(const u64* p) {
    return __hip_atomic_load(p, __ATOMIC_RELAXED, __HIP_MEMORY_SCOPE_AGENT);
}
__device__ __forceinline__ void llc_store64(u64* p, u64 v) {
    __hip_atomic_store(p, v, __ATOMIC_RELAXED, __HIP_MEMORY_SCOPE_AGENT);
}
__device__ __forceinline__ unsigned llc_load32(const unsigned* p) {
    return __hip_atomic_load(p, __ATOMIC_RELAXED, __HIP_MEMORY_SCOPE_AGENT);
}
__device__ __forceinline__ void llc_store32(unsigned* p, unsigned v) {
    __hip_atomic_store(p, v, __ATOMIC_RELAXED, __HIP_MEMORY_SCOPE_AGENT);
}

// ---------------- fp32 -> bf16 convert (8 elems/thread) ----------------
__global__ void k_f32_to_bf16(const float* __restrict__ src,
                              __hip_bfloat16* __restrict__ dst, int n8) {
    int i = blockIdx.x * blockDim.x + threadIdx.x;
    if (i >= n8) return;
    const float4* s = (const float4*)src + (size_t)i * 2;
    float4 a = s[0], b = s[1];
    union { unsigned short u[8]; uint4 v; } o;
    o.u[0] = bf_bits(__float2bfloat16(a.x));
    o.u[1] = bf_bits(__float2bfloat16(a.y));
    o.u[2] = bf_bits(__float2bfloat16(a.z));
    o.u[3] = bf_bits(__float2bfloat16(a.w));
    o.u[4] = bf_bits(__float2bfloat16(b.x));
    o.u[5] = bf_bits(__float2bfloat16(b.y));
    o.u[6] = bf_bits(__float2bfloat16(b.z));
    o.u[7] = bf_bits(__float2bfloat16(b.w));
    *((uint4*)dst + i) = o.v;
}

// ---------------- embedding gather + bf16 convert ----------------
__global__ void k_gather(const int* __restrict__ xs, const float* __restrict__ emb,
                         __hip_bfloat16* __restrict__ e_bf) {
    int tid = blockIdx.x * 256 + threadIdx.x;
    int r = tid >> 6, ch = tid & 63;
    int v = xs[r];
    const float4* s = (const float4*)(emb + (size_t)v * DE + ch * 8);
    float4 a = s[0], b = s[1];
    union { unsigned short u[8]; uint4 v4; } o;
    o.u[0] = bf_bits(__float2bfloat16(a.x));
    o.u[1] = bf_bits(__float2bfloat16(a.y));
    o.u[2] = bf_bits(__float2bfloat16(a.z));
    o.u[3] = bf_bits(__float2bfloat16(a.w));
    o.u[4] = bf_bits(__float2bfloat16(b.x));
    o.u[5] = bf_bits(__float2bfloat16(b.y));
    o.u[6] = bf_bits(__float2bfloat16(b.z));
    o.u[7] = bf_bits(__float2bfloat16(b.w));
    *((uint4*)(e_bf + (size_t)r * DE) + ch) = o.v4;
}

// ---------------- x_gates GEMM -> permuted bf16 layout ----------------
// xgp[t][blk][gate][unit][batch] : (((t*128+blk)*4+g)*8+u)*64 + b
__global__ void k_gemm_xg(const __hip_bfloat16* __restrict__ A,   // [16384][512]
                          const __hip_bfloat16* __restrict__ Bt,  // [4096][512]
                          const float* __restrict__ bih, const float* __restrict__ bhh,
                          __hip_bfloat16* __restrict__ xgp) {
    __shared__ __align__(16) __hip_bfloat16 sA[128 * 32];
    __shared__ __align__(16) __hip_bfloat16 sB[128 * 32];
    const int bm = blockIdx.x >> 5;    // 128 M-tiles
    const int bn = blockIdx.x & 31;    // 32 N-tiles
    const int tid = threadIdx.x;
    const int l = tid & 63, w = tid >> 6;
    const int wm = w >> 1, wn = w & 1;
    const int lrow = l & 15, lq = l >> 4;

    f32x4 acc[4][4] = {};

    for (int kb = 0; kb < 512; kb += 32) {
#pragma unroll
        for (int q = 0; q < 2; ++q) {
            int c = q * 256 + tid;
            int row = c >> 2, seg = c & 3;
            async_copy16(A + (size_t)(bm * 128 + row) * 512 + kb + seg * 8, &sA[c * 8]);
            async_copy16(Bt + (size_t)(bn * 128 + row) * 512 + kb + seg * 8, &sB[c * 8]);
        }
        __syncthreads();
        bf16x8 af[4], bq[4];
#pragma unroll
        for (int mt = 0; mt < 4; ++mt)
            af[mt] = *(const bf16x8*)&sA[(wm * 64 + mt * 16 + lrow) * 32 + lq * 8];
#pragma unroll
        for (int nt = 0; nt < 4; ++nt)
            bq[nt] = *(const bf16x8*)&sB[(wn * 64 + nt * 16 + lrow) * 32 + lq * 8];
#pragma unroll
        for (int mt = 0; mt < 4; ++mt)
#pragma unroll
            for (int nt = 0; nt < 4; ++nt)
                acc[mt][nt] = __builtin_amdgcn_mfma_f32_16x16x32_bf16(
                    af[mt], bq[nt], acc[mt][nt], 0, 0, 0);
        __syncthreads();
    }

#pragma unroll
    for (int nt = 0; nt < 4; ++nt) {
        int n = bn * 128 + wn * 64 + nt * 16 + lrow;
        int g = n >> 10, j = n & 1023, blk = j >> 3, u = j & 7;
        float bias = bih[n] + bhh[n];
#pragma unroll
        for (int mt = 0; mt < 4; ++mt) {
#pragma unroll
            for (int r = 0; r < 4; ++r) {
                int m = bm * 128 + wm * 64 + mt * 16 + lq * 4 + r;
                int t = m >> 6, b = m & 63;
                xgp[(((size_t)(t * NBLK + blk) * 4 + g) * 8 + u) * 64 + b] =
                    __float2bfloat16(acc[mt][nt][r] + bias);
            }
        }
    }
}

// ---------------- persistent LSTM recurrence ----------------
// 128 blocks x 256 thr; block owns units j0=8*bk (32 gate rows).
// Whh slice LDS-resident (64 KB); c register-resident; h exchanged through the
// LLC via 8B/16B system-scope stores, triple-buffered, chunk-major layout.
//
// Head (unchanged from round 5): 32 inline-asm global_load_dwordx4 full-K
// h prefetch, one vmcnt(0), MFMA loop. Proven ~1 LLC latency (VGPR 124).
//
// TAIL RESTRUCTURE (this round): the old tail was
//   barrier - h-store(tid<128) - vmcnt(0)[waits out-store RMW acks too!]
//   - barrier - flag - poll(tid<128, s_sleep) - barrier
// New tail:
//   barrier(sPack) - wave0: h-store(64x dwordx4) ; all: out stores ;
//   wave0: vmcnt(4)[waits ONLY h-store: issue-order counting] - flag ;
//   ALL waves busy-poll all 128 flags (lane l -> flags[2l,2l+1], 8B load)
// Deletes 2 of 3 barriers, removes out-store HBM RMW ack from the critical
// drain (they retire in background), removes s_sleep quantization.
// Safety: memory-clobber asm pins h-store < out-stores < vmcnt(4) < flag;
// a wave passes the poll only after its OWN flag (posted after wave0 read
// sPack) -> no sPack WAR; flag t+2 still implies step-t reads done -> the
// triple-buffer WAR argument is unchanged.
__global__ void __launch_bounds__(256, 1) k_lstm(
        const __hip_bfloat16* __restrict__ xgp,   // [256][128][4][8][64]
        const __hip_bfloat16* __restrict__ Whh,   // [4096][1024] row-major
        __hip_bfloat16* __restrict__ hbuf,        // 3 x 65536 elems, chunk-major
        float* __restrict__ out,
        unsigned* __restrict__ flags) {           // [128], zeroed per call
    __shared__ __hip_bfloat16 sW[32768];          // 64 KB: [nt2][kb32][q4][col16][8]
    __shared__ __align__(16) __hip_bfloat16 sPack[512];
    const int tid = threadIdx.x, l = tid & 63, w = tid >> 6;
    const int lrow = l & 15, lq = l >> 4;
    const int bk = blockIdx.x;

    // load Whh slice -> LDS, frag-contiguous
#pragma unroll
    for (int f = 0; f < 16; ++f) {
        int fi = f * 256 + tid;                  // frag index 0..4095
        int col = fi & 15, q = (fi >> 4) & 3, kb = (fi >> 6) & 31, nt = fi >> 11;
        int g = (nt * 16 + col) >> 3, u = col & 7;
        async_copy16(Whh + (size_t)(g * DH + bk * 8 + u) * DH + kb * 32 + q * 8,
                     &sW[fi * 8]);
    }
    // zero my slice of h buffer 0 through the LLC
    if (tid < 128)
        llc_store64((u64*)hbuf + bk * 128 + tid, 0ull);
    asm volatile("s_waitcnt vmcnt(0)" ::: "memory");
    __syncthreads();
    if (tid == 0) llc_store32(&flags[bk], 1u);
    if (tid < 128)
        while (llc_load32(&flags[tid]) < 1u) __builtin_amdgcn_s_sleep(2);
    __syncthreads();

    const int u = l & 7, halfsel = (l >> 3) & 1;
    const int b0 = w * 16 + lq * 4;
    const int aib = lq * 128 + w * 32 + lrow * 2;   // u64 index within a k-chunk
    const unsigned aib8 = (unsigned)(aib * 8);      // byte offset within a chunk
    const int jout = bk * 8 + u;
    const u64* f64 = (const u64*)flags;
    float creg[4] = {0.f, 0.f, 0.f, 0.f};

    for (int t = 0; t < T_STEPS; ++t) {
        const u64* hin  = (const u64*)hbuf + (size_t)(t % 3) * 16384;
        u64*       hout = (u64*)hbuf + (size_t)((t + 1) % 3) * 16384;
        u64*       hob  = hout + bk * 128;       // this block's 1KB h slice

        // this step's xg (read-only, plain cached loads)
        const __hip_bfloat16* xgt = xgp + (size_t)t * (NBLK * 2048) + (size_t)bk * 2048;
        ushort4 x0 = *(const ushort4*)(xgt + (halfsel * 8 + u) * 64 + b0);
        ushort4 x1 = *(const ushort4*)(xgt + ((2 + halfsel) * 8 + u) * 64 + b0);

        // Full-K h prefetch via inline-asm loads: 32 x global_load_dwordx4,
        // all in flight at once, ONE wait. sc0 sc1 = coherent (LLC) read.
        bf16x8 afr[32];
#pragma unroll
        for (int p = 0; p < 32; ++p) {
            unsigned voff = aib8 + (unsigned)(p * 4096);
            asm volatile("global_load_dwordx4 %0, %1, %2 sc0 sc1"
                         : "=v"(afr[p])
                         : "v"(voff), "s"(hin));
        }
        asm volatile("s_waitcnt vmcnt(0)" ::: "memory");
        __builtin_amdgcn_sched_barrier(0);       // rule #18: keep MFMAs below

        f32x4 a00 = {}, a01 = {}, a10 = {}, a11 = {};
#pragma unroll
        for (int kb = 0; kb < 32; ++kb) {
            bf16x8 b0f = *(const bf16x8*)&sW[(kb * 4 + lq) * 128 + lrow * 8];
            bf16x8 b1f = *(const bf16x8*)&sW[16384 + (kb * 4 + lq) * 128 + lrow * 8];
            if (kb & 1) {
                a01 = __builtin_amdgcn_mfma_f32_16x16x32_bf16(afr[kb], b0f, a01, 0, 0, 0);
                a11 = __builtin_amdgcn_mfma_f32_16x16x32_bf16(afr[kb], b1f, a11, 0, 0, 0);
            } else {
                a00 = __builtin_amdgcn_mfma_f32_16x16x32_bf16(afr[kb], b0f, a00, 0, 0, 0);
                a10 = __builtin_amdgcn_mfma_f32_16x16x32_bf16(afr[kb], b1f, a10, 0, 0, 0);
            }
        }
        f32x4 A0 = a00 + a01, A1 = a10 + a11;

        const unsigned short xs0[4] = {x0.x, x0.y, x0.z, x0.w};
        const unsigned short xs1[4] = {x1.x, x1.y, x1.z, x1.w};
        float hreg[4] = {0.f, 0.f, 0.f, 0.f};
#pragma unroll
        for (int r = 0; r < 4; ++r) {
            float v0 = A0[r] + b2f(xs0[r]);
            float v1 = A1[r] + b2f(xs1[r]);
            float p0 = __shfl_xor(v0, 8, 64);
            float p1 = __shfl_xor(v1, 8, 64);
            float ipre = halfsel ? p0 : v0;
            float fpre = halfsel ? v0 : p0;
            float gpre = halfsel ? p1 : v1;
            float opre = halfsel ? v1 : p1;
            if (!halfsel) {
                float ig = 1.0f / (1.0f + __expf(-ipre));
                float fg = 1.0f / (1.0f + __expf(-fpre));
                float gg = tanhf(gpre);
                float og = 1.0f / (1.0f + __expf(-opre));
                float cnew = fg * creg[r] + ig * gg;
                float hnew = og * tanhf(cnew);
                creg[r] = cnew;
                hreg[r] = hnew;
                sPack[(b0 + r) * 8 + u] = __float2bfloat16(hnew);
            }
        }

        __syncthreads();                         // sPack visible block-wide (only barrier/step)

        if (t == T_STEPS - 1) {
            if (!halfsel) {
#pragma unroll
                for (int r = 0; r < 4; ++r) {
                    int b = b0 + r;
                    out[(size_t)t * (BATCH * DH) + b * DH + jout] = hreg[r];
                    out[(size_t)T_STEPS * BATCH * DH + b * DH + jout] = hreg[r];
                    out[(size_t)T_STEPS * BATCH * DH + BATCH * DH + b * DH + jout] = creg[r];
                }
            }
        } else {
            // wave 0 alone stores the block's entire 1KB h slice (issued FIRST
            // so it is the oldest outstanding VMEM op of this wave)
            if (w == 0) {
                u32x4 hq = *(const u32x4*)&sPack[l * 8];   // 16B per lane
                asm volatile("global_store_dwordx4 %0, %1, %2 sc0 sc1"
                             :: "v"((unsigned)(l * 16)), "v"(hq), "s"(hob)
                             : "memory");
            }
            // out stores (all waves): issued after h-store, NOT waited on —
            // their HBM RMW acks retire in the background during the poll
            if (!halfsel) {
#pragma unroll
                for (int r = 0; r < 4; ++r)
                    out[(size_t)t * (BATCH * DH) + (b0 + r) * DH + jout] = hreg[r];
            }
            if (w == 0) {
                // vmcnt counts in issue order: wave0 has 1 h-store + 4 out
                // stores outstanding; vmcnt(4) waits exactly the h-store.
                asm volatile("s_waitcnt vmcnt(4)" ::: "memory");
                if (tid == 0) llc_store32(&flags[bk], (unsigned)(t + 2));
            }
            // all-wave busy poll: lane l checks flags[2l], flags[2l+1]
            const unsigned need = (unsigned)(t + 2);
            while (true) {
                u64 fv = llc_load64(f64 + l);
                if ((unsigned)fv >= need && (unsigned)(fv >> 32) >= need) break;
            }
            asm volatile("" ::: "memory");       // no hoisting of next-step loads
        }
    }
}

extern "C" void kernel_launch(void* const* d_in, const int* in_sizes, int n_in,
                              void* d_out, int out_size, void* d_ws, size_t ws_size,
                              hipStream_t stream) {
    const int*   xs  = (const int*)d_in[0];
    const float* emb = (const float*)d_in[1];
    const float* Wih = (const float*)d_in[2];
    const float* Whh = (const float*)d_in[3];
    const float* bih = (const float*)d_in[4];
    const float* bhh = (const float*)d_in[5];
    float* out = (float*)d_out;
    char*  ws  = (char*)d_ws;

    __hip_bfloat16* Wih_bf = (__hip_bfloat16*)(ws);                  //  4 MB
    __hip_bfloat16* Whh_bf = (__hip_bfloat16*)(ws + 4194304);        //  8 MB
    __hip_bfloat16* e_bf   = (__hip_bfloat16*)(ws + 12582912);       // 16 MB
    __hip_bfloat16* xgp    = (__hip_bfloat16*)(ws + 29360128);       // 128 MB
    __hip_bfloat16* hbuf   = (__hip_bfloat16*)(ws + 163577856);      // 384 KB (3 bufs)
    unsigned*       flags  = (unsigned*)(ws + 163971072);            // 512 B

    hipMemsetAsync(flags, 0, 512, stream);
    k_f32_to_bf16<<<1024, 256, 0, stream>>>(Wih, Wih_bf, 2097152 / 8);
    k_f32_to_bf16<<<2048, 256, 0, stream>>>(Whh, Whh_bf, 4194304 / 8);
    k_gather<<<4096, 256, 0, stream>>>(xs, emb, e_bf);
    k_gemm_xg<<<4096, 256, 0, stream>>>(e_bf, Wih_bf, bih, bhh, xgp);
    k_lstm<<<NBLK, 256, 0, stream>>>(xgp, Whh_bf, hbuf, out, flags);
}